// Round 2
// baseline (249.011 us; speedup 1.0000x reference)
//
#include <hip/hip_runtime.h>
#include <cstdint>

#define HB 8
#define CM 128
#define NHEAD 8
#define NPT 8
#define DHD 16
#define HS 64
#define WS 64
#define LTOT 4096

__device__ __forceinline__ float fast_tanh(float x) {
  float e = __expf(2.0f * x);
  return 1.0f - 2.0f / (e + 1.0f);
}

// C[l][n] = sum_k A[b][k][l] * W[k][n] + bias[n]
// A layout: [b][128 k][4096 l] (l contiguous). Tile 64 l x N n, micro 4x4.
// threads = 16 * (N/4). K=128 staged once into LDS.
// OUT_MODE 0: value layout out[((b*8 + n/16)*4096 + l)*16 + n%16]
// OUT_MODE 1: [b][n][l]   out[(b*128 + n)*4096 + l]
// OUT_MODE 2: row-major   out[(b*4096 + l)*N + n]
template <int N, int OUT_MODE>
__global__ __launch_bounds__(16 * (N / 4)) void gemm_tile(
    const float* __restrict__ A, const float* __restrict__ W,
    const float* __restrict__ bias, float* __restrict__ out) {
  __shared__ float S[128][64];
  constexpr int NT = 16 * (N / 4);
  const int b = blockIdx.y;
  const int l0 = blockIdx.x * 64;
  const int t = threadIdx.x;

  const float* Ab = A + (size_t)b * (CM * LTOT) + l0;
#pragma unroll
  for (int i = 0; i < 2048 / NT; i++) {
    int idx = t + NT * i;             // over 2048 float4 = 128k x 16 quads
    int k = idx >> 4, lq = idx & 15;
    float4 v = *(const float4*)(Ab + (size_t)k * LTOT + lq * 4);
    *(float4*)&S[k][lq * 4] = v;
  }
  __syncthreads();

  const int tn = t % (N / 4);
  const int tl = t / (N / 4);
  float acc[4][4];
#pragma unroll
  for (int i = 0; i < 4; i++)
#pragma unroll
    for (int j = 0; j < 4; j++) acc[i][j] = 0.0f;

  const float* Wp = W + tn * 4;
#pragma unroll 8
  for (int k = 0; k < 128; k++) {
    const float4 w4 = *(const float4*)(Wp + (size_t)k * N);
    const float4 q4 = *(const float4*)&S[k][tl * 4];
    const float q[4] = {q4.x, q4.y, q4.z, q4.w};
    const float wr[4] = {w4.x, w4.y, w4.z, w4.w};
#pragma unroll
    for (int i = 0; i < 4; i++)
#pragma unroll
      for (int j = 0; j < 4; j++) acc[i][j] += q[i] * wr[j];
  }

  const int lbase = l0 + tl * 4;
  if (OUT_MODE == 0) {
#pragma unroll
    for (int j = 0; j < 4; j++) {
      const int n = tn * 4 + j;
      const float bv = bias[n];
      float* op = out + (((size_t)b * NHEAD + (n >> 4)) * LTOT + lbase) * DHD + (n & 15);
#pragma unroll
      for (int i = 0; i < 4; i++) op[i * DHD] = acc[i][j] + bv;
    }
  } else if (OUT_MODE == 1) {
#pragma unroll
    for (int j = 0; j < 4; j++) {
      const int n = tn * 4 + j;
      const float bv = bias[n];
      float4 v = {acc[0][j] + bv, acc[1][j] + bv, acc[2][j] + bv, acc[3][j] + bv};
      *(float4*)(out + ((size_t)b * CM + n) * LTOT + lbase) = v;
    }
  } else {
    const float4 b4 = *(const float4*)(bias + tn * 4);
#pragma unroll
    for (int i = 0; i < 4; i++) {
      float4 v = {acc[i][0] + b4.x, acc[i][1] + b4.y, acc[i][2] + b4.z, acc[i][3] + b4.w};
      *(float4*)(out + ((size_t)b * LTOT + lbase + i) * N + tn * 4) = v;
    }
  }
}

// One thread per (b, l, head, point). p = t&7 (lane-local for shfl reductions).
// Block: 4 l x 8 h x 8 p = 256 threads. No LDS.
__global__ __launch_bounds__(256) void sampler(const float* __restrict__ value,
                                               const float* __restrict__ offraw,
                                               const float* __restrict__ attnraw,
                                               float* __restrict__ attout) {
  const int t = threadIdx.x;
  const int p = t & 7;
  const int h = (t >> 3) & 7;
  const int li = t >> 6;
  const int b = blockIdx.y;
  const int l = blockIdx.x * 4 + li;

  const size_t bl = (size_t)b * LTOT + l;
  const float2 off2 = *(const float2*)(offraw + bl * 128 + h * 16 + p * 2);
  const float logit = attnraw[bl * 64 + h * 8 + p];

  const float xf = (float)(l & (WS - 1));
  const float yf = (float)(l >> 6);
  const float px = xf + 10.0f * fast_tanh(off2.x);
  const float py = yf + 10.0f * fast_tanh(off2.y);

  // softmax across the 8 p-lanes (butterfly)
  float m = logit;
  m = fmaxf(m, __shfl_xor(m, 1));
  m = fmaxf(m, __shfl_xor(m, 2));
  m = fmaxf(m, __shfl_xor(m, 4));
  float e = __expf(logit - m);
  float ssum = e;
  ssum += __shfl_xor(ssum, 1);
  ssum += __shfl_xor(ssum, 2);
  ssum += __shfl_xor(ssum, 4);
  const float aw = e / ssum;

  const float x0f = floorf(px), y0f = floorf(py);
  const float fx = px - x0f, fy = py - y0f;
  const int ix = (int)x0f, iy = (int)y0f;

  const float vx0 = ((unsigned)ix < WS) ? 1.0f : 0.0f;
  const float vx1 = ((unsigned)(ix + 1) < WS) ? 1.0f : 0.0f;
  const float vy0 = ((unsigned)iy < HS) ? 1.0f : 0.0f;
  const float vy1 = ((unsigned)(iy + 1) < HS) ? 1.0f : 0.0f;

  const float w00 = aw * (1.0f - fx) * (1.0f - fy) * vx0 * vy0;
  const float w10 = aw * fx * (1.0f - fy) * vx1 * vy0;
  const float w01 = aw * (1.0f - fx) * fy * vx0 * vy1;
  const float w11 = aw * fx * fy * vx1 * vy1;

  const int x0c = min(max(ix, 0), WS - 1);
  const int x1c = min(max(ix + 1, 0), WS - 1);
  const int y0c = min(max(iy, 0), HS - 1);
  const int y1c = min(max(iy + 1, 0), HS - 1);

  const float* vb = value + ((size_t)b * NHEAD + h) * (LTOT * DHD);
  const float4* p00 = (const float4*)(vb + (size_t)(y0c * WS + x0c) * DHD);
  const float4* p10 = (const float4*)(vb + (size_t)(y0c * WS + x1c) * DHD);
  const float4* p01 = (const float4*)(vb + (size_t)(y1c * WS + x0c) * DHD);
  const float4* p11 = (const float4*)(vb + (size_t)(y1c * WS + x1c) * DHD);

  float o[DHD];
#pragma unroll
  for (int q = 0; q < 4; q++) {
    const float4 a = p00[q], c = p10[q], d = p01[q], f = p11[q];
    o[q * 4 + 0] = w00 * a.x + w10 * c.x + w01 * d.x + w11 * f.x;
    o[q * 4 + 1] = w00 * a.y + w10 * c.y + w01 * d.y + w11 * f.y;
    o[q * 4 + 2] = w00 * a.z + w10 * c.z + w01 * d.z + w11 * f.z;
    o[q * 4 + 3] = w00 * a.w + w10 * c.w + w01 * d.w + w11 * f.w;
  }

  // sum over the 8 points (butterfly across p-lanes)
#pragma unroll
  for (int d = 0; d < DHD; d++) {
    o[d] += __shfl_xor(o[d], 1);
    o[d] += __shfl_xor(o[d], 2);
    o[d] += __shfl_xor(o[d], 4);
  }

  // lanes cooperatively write 16 channels: lane p writes d = 2p, 2p+1
  const int c0 = h * DHD + p * 2;
  attout[((size_t)b * CM + c0) * LTOT + l] = o[p * 2];
  attout[((size_t)b * CM + c0 + 1) * LTOT + l] = o[p * 2 + 1];
}

extern "C" void kernel_launch(void* const* d_in, const int* in_sizes, int n_in,
                              void* d_out, int out_size, void* d_ws, size_t ws_size,
                              hipStream_t stream) {
  const float* nbr    = (const float*)d_in[0];
  const float* ext    = (const float*)d_in[1];
  const float* W_val  = (const float*)d_in[2];
  const float* b_val  = (const float*)d_in[3];
  const float* W_off  = (const float*)d_in[4];
  const float* b_off  = (const float*)d_in[5];
  const float* W_attn = (const float*)d_in[6];
  const float* b_attn = (const float*)d_in[7];
  const float* W_out  = (const float*)d_in[8];
  const float* b_out  = (const float*)d_in[9];
  float* out = (float*)d_out;

  float* value   = (float*)d_ws;                                   // 16 MB [b][h][l][16]
  float* offraw  = value + (size_t)HB * NHEAD * LTOT * DHD;        // 16 MB [b][l][128]
  float* attnraw = offraw + (size_t)HB * LTOT * CM;                // 8 MB  [b][l][64]
  float* attout  = attnraw + (size_t)HB * LTOT * (NHEAD * NPT);    // 16 MB [b][c][l]

  dim3 gg(LTOT / 64, HB);
  gemm_tile<128, 0><<<gg, 512, 0, stream>>>(nbr, W_val, b_val, value);
  gemm_tile<128, 2><<<gg, 512, 0, stream>>>(ext, W_off, b_off, offraw);
  gemm_tile<64, 2><<<gg, 256, 0, stream>>>(ext, W_attn, b_attn, attnraw);
  sampler<<<dim3(LTOT / 4, HB), 256, 0, stream>>>(value, offraw, attnraw, attout);
  gemm_tile<128, 1><<<gg, 512, 0, stream>>>(attout, W_out, b_out, out);
}